// Round 1
// baseline (33515.036 us; speedup 1.0000x reference)
//
#include <hip/hip_runtime.h>

// ---------------------------------------------------------------------------
// MultilayerGRU: B=32, S=4096, H=256, O=256, L=2
// Structure per time-chunk (Tc=256, 16 chunks):
//   xgemm  : x-side preactivations  [Tc*32, 256] x [256, 768] -> bf16 XS buffer
//   gru_scan: sequential 256-step scan, 2 WGs x 16 samples, MFMA 16x16x32 bf16,
//             Whz/Whr in registers, Whg in LDS (xor-swizzled), h master in fp32 regs
//   xgemm  : layer-1 x-side from h0 chunk
//   gru_scan: layer 1
//   xgemm  : output projection -> d_out (fp32)
// ---------------------------------------------------------------------------

typedef __attribute__((ext_vector_type(8))) short short8;
typedef __attribute__((ext_vector_type(4))) float f32x4;

#define TC      256
#define NCHUNK  16
#define SSZ     4096

__device__ __forceinline__ float bf2f(unsigned short u) {
    union { unsigned int i; float f; } v; v.i = ((unsigned int)u) << 16; return v.f;
}
__device__ __forceinline__ unsigned short f2bf(float f) {
    union { float f; unsigned int i; } v; v.f = f;
    v.i += 0x7fff + ((v.i >> 16) & 1);   // RNE
    return (unsigned short)(v.i >> 16);
}
__device__ __forceinline__ short8 cvt8(const float* p) {
    float4 a = *(const float4*)p;
    float4 b = *(const float4*)(p + 4);
    short8 r;
    r[0] = (short)f2bf(a.x); r[1] = (short)f2bf(a.y);
    r[2] = (short)f2bf(a.z); r[3] = (short)f2bf(a.w);
    r[4] = (short)f2bf(b.x); r[5] = (short)f2bf(b.y);
    r[6] = (short)f2bf(b.z); r[7] = (short)f2bf(b.w);
    return r;
}

// ---------------------------------------------------------------------------
// Generic K=256 GEMM: out[i][j] = sum_k A[i][k] * W[j][k] + bias[j]
// a_mode 0: A = fp32 x, row i -> (tc=i>>5, b=i&31), addr (b*4096 + c0+tc)*256
// a_mode 1: A = bf16 H chunk, row i contiguous at i*256
// o_mode 0: bf16 store at i*Ncols + j      (XS buffer)
// o_mode 1: fp32 store at b*(S*256) + (c0+tc)*256 + j   (final y)
// W rows stacked: j<256 -> w0, <512 -> w1, else w2 (biases likewise)
// ---------------------------------------------------------------------------
__global__ __launch_bounds__(256, 2) void xgemm(
    const void* __restrict__ Aptr, int a_mode, int c0,
    const float* __restrict__ w0, const float* __restrict__ w1, const float* __restrict__ w2,
    const float* __restrict__ b0, const float* __restrict__ b1, const float* __restrict__ b2,
    int Ncols, void* __restrict__ Optr, int o_mode)
{
    __shared__ unsigned short Alds[64 * 256];
    __shared__ unsigned short Wlds[64 * 256];
    const int tid = threadIdx.x;
    const int mt = blockIdx.x, jt = blockIdx.y;

    // stage A tile (64 rows x 256 k) as bf16, xor-swizzled in 8-elem blocks
    for (int idx = tid; idx < 4096; idx += 256) {
        int row = idx >> 6;
        int kq  = (idx & 63) << 2;                       // 4-elem granularity
        int sw  = row * 256 + (((((kq >> 3) ^ (row & 7)) << 3)) | (kq & 7));
        if (a_mode == 0) {
            int i = mt * 64 + row; int tc = i >> 5, b = i & 31;
            const float* p = (const float*)Aptr + ((size_t)b * SSZ + (size_t)(c0 + tc)) * 256 + kq;
            float4 v = *(const float4*)p;
            ushort4 u; u.x = f2bf(v.x); u.y = f2bf(v.y); u.z = f2bf(v.z); u.w = f2bf(v.w);
            *(ushort4*)&Alds[sw] = u;
        } else {
            const unsigned short* p = (const unsigned short*)Aptr + (size_t)(mt * 64 + row) * 256 + kq;
            *(ushort4*)&Alds[sw] = *(const ushort4*)p;
        }
    }
    // stage W tile (64 j-rows x 256 k)
    for (int idx = tid; idx < 4096; idx += 256) {
        int row = idx >> 6;
        int kq  = (idx & 63) << 2;
        int j   = jt * 64 + row;
        const float* wp = (j < 256) ? w0 : ((j < 512) ? w1 : w2);
        const float* p  = wp + (size_t)(j & 255) * 256 + kq;
        float4 v = *(const float4*)p;
        ushort4 u; u.x = f2bf(v.x); u.y = f2bf(v.y); u.z = f2bf(v.z); u.w = f2bf(v.w);
        int sw = row * 256 + (((((kq >> 3) ^ (row & 7)) << 3)) | (kq & 7));
        *(ushort4*)&Wlds[sw] = u;
    }
    __syncthreads();

    const int lane = tid & 63, wv = tid >> 6;            // 4 waves
    const int cl = lane & 15, qr = lane >> 4;
    f32x4 acc[4];
    #pragma unroll
    for (int nt = 0; nt < 4; ++nt) acc[nt] = (f32x4){0.f, 0.f, 0.f, 0.f};

    #pragma unroll
    for (int kt = 0; kt < 8; ++kt) {
        int kb = kt * 4 + qr;
        short8 af = *(const short8*)&Alds[(wv * 16 + cl) * 256 + ((kb ^ (cl & 7)) << 3)];
        #pragma unroll
        for (int nt = 0; nt < 4; ++nt) {
            short8 bf = *(const short8*)&Wlds[(nt * 16 + cl) * 256 + ((kb ^ (cl & 7)) << 3)];
            acc[nt] = __builtin_amdgcn_mfma_f32_16x16x32_bf16(af, bf, acc[nt], 0, 0, 0);
        }
    }

    #pragma unroll
    for (int nt = 0; nt < 4; ++nt) {
        int j = jt * 64 + nt * 16 + cl;
        const float* bp = (j < 256) ? b0 : ((j < 512) ? b1 : b2);
        float bias = bp[j & 255];
        #pragma unroll
        for (int r = 0; r < 4; ++r) {
            float v = acc[nt][r] + bias;
            int m = mt * 64 + wv * 16 + qr * 4 + r;      // C/D: row=(lane>>4)*4+reg, col=lane&15
            if (o_mode == 0) {
                ((unsigned short*)Optr)[(size_t)m * Ncols + j] = f2bf(v);
            } else {
                int tc = m >> 5, b = m & 31;
                ((float*)Optr)[(size_t)b * (SSZ * 256) + (size_t)(c0 + tc) * 256 + j] = v;
            }
        }
    }
}

// ---------------------------------------------------------------------------
// Sequential GRU scan over one time chunk. grid=2 (16 samples each), 512 thr.
// Per step: pass1 z,r = sigmoid(XS + h@W^T); A2 = (h*r); pass2 g = tanh(XS + A2@Whg^T);
// h = z*h + (1-z)*g. fp32 h master in registers; bf16 only at MFMA operands.
// ---------------------------------------------------------------------------
__global__ __launch_bounds__(512, 2) void gru_scan(
    const unsigned short* __restrict__ XS,     // [TC][32][768] bf16 (z|r|g)
    unsigned short* __restrict__ Hout,         // [TC][32][256] bf16
    float* __restrict__ hstate,                // ws [2][32][256] fp32
    const float* __restrict__ hidden_in,       // d_in[1] [32][2][256] fp32
    const float* __restrict__ Whz, const float* __restrict__ Whr, const float* __restrict__ Whg,
    int layer, int first_chunk, int last_chunk,
    float* __restrict__ dout_tail)             // d_out + B*S*O, [32][2][256]
{
    __shared__ unsigned short Wg[65536];       // Whg [n][k] bf16, swizzled (128 KB)
    __shared__ unsigned short hA[4096];        // h   [m][k] bf16, A-layout, swizzled
    __shared__ unsigned short A2[4096];        // h*r [m][k]

    const int tid  = threadIdx.x;
    const int wg   = blockIdx.x;               // sample group: b in [wg*16, wg*16+16)
    const int lane = tid & 63, wv = tid >> 6;  // 8 waves
    const int cl   = lane & 15, qr = lane >> 4;
    const int colb = wv * 32 + cl;             // wave owns cols [wv*32, wv*32+32)
    const int swl  = cl & 7;

    // stage Whg -> LDS (xor swizzle on 8-elem k-blocks vs n&7)
    for (int idx = tid; idx < 8192; idx += 512) {
        int n = idx >> 5, kb = idx & 31;
        const float* p = Whg + (size_t)n * 256 + kb * 8;
        float4 v0 = *(const float4*)p;
        float4 v1 = *(const float4*)(p + 4);
        ushort4 u0, u1;
        u0.x = f2bf(v0.x); u0.y = f2bf(v0.y); u0.z = f2bf(v0.z); u0.w = f2bf(v0.w);
        u1.x = f2bf(v1.x); u1.y = f2bf(v1.y); u1.z = f2bf(v1.z); u1.w = f2bf(v1.w);
        int sw = n * 256 + ((kb ^ (n & 7)) << 3);
        *(ushort4*)&Wg[sw]     = u0;
        *(ushort4*)&Wg[sw + 4] = u1;
    }

    // z/r weight B-fragments resident in registers: 32 x short8 = 128 VGPR/lane
    short8 wzf[2][8], wrf[2][8];
    #pragma unroll
    for (int nt = 0; nt < 2; ++nt) {
        int n = colb + nt * 16;
        #pragma unroll
        for (int kt = 0; kt < 8; ++kt) {
            int k0 = kt * 32 + qr * 8;        // B-frag: k = (lane>>4)*8 + j, n = lane&15
            wzf[nt][kt] = cvt8(Whz + (size_t)n * 256 + k0);
            wrf[nt][kt] = cvt8(Whr + (size_t)n * 256 + k0);
        }
    }

    // init h master (fp32 regs, D-layout: row m=qr*4+r, col=colb+nt*16) + hA LDS
    float hreg[2][4];
    #pragma unroll
    for (int nt = 0; nt < 2; ++nt)
        #pragma unroll
        for (int r = 0; r < 4; ++r) {
            int m = qr * 4 + r, b = wg * 16 + m, col = colb + nt * 16;
            float h = first_chunk ? hidden_in[(size_t)b * 512 + layer * 256 + col]
                                  : hstate[layer * 8192 + b * 256 + col];
            hreg[nt][r] = h;
            int sw = m * 256 + ((((col >> 3) ^ (m & 7)) << 3) | (col & 7));
            hA[sw] = f2bf(h);
        }
    __syncthreads();

    for (int t = 0; t < TC; ++t) {
        // x-side preactivation loads for this step (issued before MFMA to hide latency)
        unsigned short xz[2][4], xr[2][4], xg[2][4];
        const unsigned short* xp = XS + (size_t)(t * 32 + wg * 16) * 768;
        #pragma unroll
        for (int nt = 0; nt < 2; ++nt)
            #pragma unroll
            for (int r = 0; r < 4; ++r) {
                size_t o = (size_t)(qr * 4 + r) * 768 + (colb + nt * 16);
                xz[nt][r] = xp[o];
                xr[nt][r] = xp[o + 256];
                xg[nt][r] = xp[o + 512];
            }

        // pass 1: z,r h-parts. A-frag: m=lane&15, k=(lane>>4)*8+j
        f32x4 az[2], ar[2];
        az[0] = (f32x4){0.f,0.f,0.f,0.f}; az[1] = az[0]; ar[0] = az[0]; ar[1] = az[0];
        #pragma unroll
        for (int kt = 0; kt < 8; ++kt) {
            int kb = kt * 4 + qr;
            short8 af = *(const short8*)&hA[cl * 256 + ((kb ^ swl) << 3)];
            az[0] = __builtin_amdgcn_mfma_f32_16x16x32_bf16(af, wzf[0][kt], az[0], 0, 0, 0);
            ar[0] = __builtin_amdgcn_mfma_f32_16x16x32_bf16(af, wrf[0][kt], ar[0], 0, 0, 0);
            az[1] = __builtin_amdgcn_mfma_f32_16x16x32_bf16(af, wzf[1][kt], az[1], 0, 0, 0);
            ar[1] = __builtin_amdgcn_mfma_f32_16x16x32_bf16(af, wrf[1][kt], ar[1], 0, 0, 0);
        }
        float zv[2][4];
        #pragma unroll
        for (int nt = 0; nt < 2; ++nt)
            #pragma unroll
            for (int r = 0; r < 4; ++r) {
                float z = az[nt][r] + bf2f(xz[nt][r]);
                zv[nt][r] = 1.0f / (1.0f + __expf(-z));
                float rr = ar[nt][r] + bf2f(xr[nt][r]);
                rr = 1.0f / (1.0f + __expf(-rr));
                int m = qr * 4 + r, col = colb + nt * 16;
                int sw = m * 256 + ((((col >> 3) ^ (m & 7)) << 3) | (col & 7));
                A2[sw] = f2bf(rr * hreg[nt][r]);
            }
        __syncthreads();

        // pass 2: g from (h*r) @ Whg^T (Whg B-frags from LDS)
        f32x4 ag[2];
        ag[0] = (f32x4){0.f,0.f,0.f,0.f}; ag[1] = ag[0];
        #pragma unroll
        for (int kt = 0; kt < 8; ++kt) {
            int kb = kt * 4 + qr;
            short8 af = *(const short8*)&A2[cl * 256 + ((kb ^ swl) << 3)];
            #pragma unroll
            for (int nt = 0; nt < 2; ++nt) {
                int n = colb + nt * 16;                  // n&7 == cl&7 == swl
                short8 bfr = *(const short8*)&Wg[n * 256 + ((kb ^ swl) << 3)];
                ag[nt] = __builtin_amdgcn_mfma_f32_16x16x32_bf16(af, bfr, ag[nt], 0, 0, 0);
            }
        }
        #pragma unroll
        for (int nt = 0; nt < 2; ++nt)
            #pragma unroll
            for (int r = 0; r < 4; ++r) {
                float g = ag[nt][r] + bf2f(xg[nt][r]);
                float s = 1.0f / (1.0f + __expf(-2.0f * g));
                g = 2.0f * s - 1.0f;                     // tanh
                float hn = zv[nt][r] * hreg[nt][r] + (1.0f - zv[nt][r]) * g;
                hreg[nt][r] = hn;
                unsigned short hb = f2bf(hn);
                int m = qr * 4 + r, col = colb + nt * 16;
                Hout[(size_t)(t * 32 + wg * 16 + m) * 256 + col] = hb;
                int sw = m * 256 + ((((col >> 3) ^ (m & 7)) << 3) | (col & 7));
                hA[sw] = hb;
            }
        __syncthreads();
    }

    // persist state across chunks; emit final hidden on last chunk
    #pragma unroll
    for (int nt = 0; nt < 2; ++nt)
        #pragma unroll
        for (int r = 0; r < 4; ++r) {
            int m = qr * 4 + r, b = wg * 16 + m, col = colb + nt * 16;
            hstate[layer * 8192 + b * 256 + col] = hreg[nt][r];
            if (last_chunk)
                dout_tail[(size_t)b * 512 + layer * 256 + col] = hreg[nt][r];
        }
}

extern "C" void kernel_launch(void* const* d_in, const int* in_sizes, int n_in,
                              void* d_out, int out_size, void* d_ws, size_t ws_size,
                              hipStream_t stream) {
    const float* x   = (const float*)d_in[0];
    const float* h0  = (const float*)d_in[1];
    const float* Wxz = (const float*)d_in[2];
    const float* Whz = (const float*)d_in[3];
    const float* bz  = (const float*)d_in[4];
    const float* Wxr = (const float*)d_in[5];
    const float* Whr = (const float*)d_in[6];
    const float* br  = (const float*)d_in[7];
    const float* Wxg = (const float*)d_in[8];
    const float* Whg = (const float*)d_in[9];
    const float* bg  = (const float*)d_in[10];
    const float* Why = (const float*)d_in[11];
    const float* by  = (const float*)d_in[12];
    float* out = (float*)d_out;

    char* ws = (char*)d_ws;
    unsigned short* bufA = (unsigned short*)(ws);                    // 12,582,912 B
    unsigned short* bufB = (unsigned short*)(ws + 12582912);         // 12,582,912 B
    unsigned short* Hc0  = (unsigned short*)(ws + 25165824);         //  4,194,304 B
    unsigned short* Hc1  = (unsigned short*)(ws + 29360128);         //  4,194,304 B
    float*          hst  = (float*)(ws + 33554432);                  //     65,536 B
    float* dout_tail = out + (size_t)32 * 4096 * 256;

    const int LW = 256 * 256;   // per-layer weight stride
    for (int c = 0; c < NCHUNK; ++c) {
        int c0 = c * TC;
        int first = (c == 0), last = (c == NCHUNK - 1);
        // layer 0 x-side
        xgemm<<<dim3(128, 12), 256, 0, stream>>>(x, 0, c0, Wxz, Wxr, Wxg, bz, br, bg,
                                                 768, bufA, 0);
        // layer 0 scan
        gru_scan<<<2, 512, 0, stream>>>(bufA, Hc0, hst, h0, Whz, Whr, Whg,
                                        0, first, last, dout_tail);
        // layer 1 x-side (input = layer-0 hidden chunk, bf16)
        xgemm<<<dim3(128, 12), 256, 0, stream>>>(Hc0, 1, c0, Wxz + LW, Wxr + LW, Wxg + LW,
                                                 bz + 256, br + 256, bg + 256, 768, bufB, 0);
        // layer 1 scan
        gru_scan<<<2, 512, 0, stream>>>(bufB, Hc1, hst, h0, Whz + LW, Whr + LW, Whg + LW,
                                        1, first, last, dout_tail);
        // output projection -> d_out (fp32)
        xgemm<<<dim3(128, 4), 256, 0, stream>>>(Hc1, 1, c0, Why, Why, Why, by, by, by,
                                                256, out, 1);
    }
}

// Round 2
// 32320.779 us; speedup vs baseline: 1.0370x; 1.0370x over previous
//
#include <hip/hip_runtime.h>

// ---------------------------------------------------------------------------
// MultilayerGRU: B=32, S=4096, H=256, O=256, L=2
// Round 2: scan restructured to 4 waves/WG, all W_h gates register-resident
// (384 VGPR), vectorized XS layout, coalesced Hout via LDS staging.
// ---------------------------------------------------------------------------

typedef __attribute__((ext_vector_type(8))) short short8;
typedef __attribute__((ext_vector_type(4))) float f32x4;

#define TC      256
#define NCHUNK  16
#define SSZ     4096

__device__ __forceinline__ float bf2f(unsigned short u) {
    union { unsigned int i; float f; } v; v.i = ((unsigned int)u) << 16; return v.f;
}
__device__ __forceinline__ unsigned short f2bf(float f) {        // RNE (setup paths)
    union { float f; unsigned int i; } v; v.f = f;
    v.i += 0x7fff + ((v.i >> 16) & 1);
    return (unsigned short)(v.i >> 16);
}
__device__ __forceinline__ unsigned short f2bf_ru(float f) {     // round-half-up (hot loop)
    union { float f; unsigned int i; } v; v.f = f;
    return (unsigned short)((v.i + 0x8000u) >> 16);
}
__device__ __forceinline__ short8 cvt8(const float* p) {
    float4 a = *(const float4*)p;
    float4 b = *(const float4*)(p + 4);
    short8 r;
    r[0] = (short)f2bf(a.x); r[1] = (short)f2bf(a.y);
    r[2] = (short)f2bf(a.z); r[3] = (short)f2bf(a.w);
    r[4] = (short)f2bf(b.x); r[5] = (short)f2bf(b.y);
    r[6] = (short)f2bf(b.z); r[7] = (short)f2bf(b.w);
    return r;
}
__device__ __forceinline__ float fsig(float x) {                 // 1/(1+e^-x)
    return __builtin_amdgcn_rcpf(1.0f + __builtin_amdgcn_exp2f(x * -1.44269504f));
}
__device__ __forceinline__ float ftanh(float x) {                // 1 - 2/(e^2x+1)
    float e = __builtin_amdgcn_exp2f(x * 2.885390082f);
    return 1.0f - 2.0f * __builtin_amdgcn_rcpf(e + 1.0f);
}

// ---------------------------------------------------------------------------
// K=256 GEMM: out[i][j] = sum_k A[i][k] * W[j][k] + bias[j]
// a_mode 0: A = fp32 x at (b*4096 + c0+tc)*256 ; a_mode 1: A = bf16 rows at i*256
// o_mode 0: bf16 store into scan-ordered XS buffer [t][wg][c:6][tid:256][8]
// o_mode 1: fp32 store at b*(S*256) + (c0+tc)*256 + j   (final y)
// ---------------------------------------------------------------------------
__global__ __launch_bounds__(256, 2) void xgemm(
    const void* __restrict__ Aptr, int a_mode, int c0,
    const float* __restrict__ w0, const float* __restrict__ w1, const float* __restrict__ w2,
    const float* __restrict__ b0, const float* __restrict__ b1, const float* __restrict__ b2,
    int Ncols, void* __restrict__ Optr, int o_mode)
{
    __shared__ unsigned short Alds[64 * 256];
    __shared__ unsigned short Wlds[64 * 256];
    const int tid = threadIdx.x;
    const int mt = blockIdx.x, jt = blockIdx.y;

    for (int idx = tid; idx < 4096; idx += 256) {
        int row = idx >> 6;
        int kq  = (idx & 63) << 2;
        int sw  = row * 256 + (((((kq >> 3) ^ (row & 7)) << 3)) | (kq & 7));
        if (a_mode == 0) {
            int i = mt * 64 + row; int tc = i >> 5, b = i & 31;
            const float* p = (const float*)Aptr + ((size_t)b * SSZ + (size_t)(c0 + tc)) * 256 + kq;
            float4 v = *(const float4*)p;
            ushort4 u; u.x = f2bf(v.x); u.y = f2bf(v.y); u.z = f2bf(v.z); u.w = f2bf(v.w);
            *(ushort4*)&Alds[sw] = u;
        } else {
            const unsigned short* p = (const unsigned short*)Aptr + (size_t)(mt * 64 + row) * 256 + kq;
            *(ushort4*)&Alds[sw] = *(const ushort4*)p;
        }
    }
    for (int idx = tid; idx < 4096; idx += 256) {
        int row = idx >> 6;
        int kq  = (idx & 63) << 2;
        int j   = jt * 64 + row;
        const float* wp = (j < 256) ? w0 : ((j < 512) ? w1 : w2);
        const float* p  = wp + (size_t)(j & 255) * 256 + kq;
        float4 v = *(const float4*)p;
        ushort4 u; u.x = f2bf(v.x); u.y = f2bf(v.y); u.z = f2bf(v.z); u.w = f2bf(v.w);
        int sw = row * 256 + (((((kq >> 3) ^ (row & 7)) << 3)) | (kq & 7));
        *(ushort4*)&Wlds[sw] = u;
    }
    __syncthreads();

    const int lane = tid & 63, wv = tid >> 6;
    const int cl = lane & 15, qr = lane >> 4;
    f32x4 acc[4];
    #pragma unroll
    for (int nt = 0; nt < 4; ++nt) acc[nt] = (f32x4){0.f, 0.f, 0.f, 0.f};

    #pragma unroll
    for (int kt = 0; kt < 8; ++kt) {
        int kb = kt * 4 + qr;
        short8 af = *(const short8*)&Alds[(wv * 16 + cl) * 256 + ((kb ^ (cl & 7)) << 3)];
        #pragma unroll
        for (int nt = 0; nt < 4; ++nt) {
            short8 bf = *(const short8*)&Wlds[(nt * 16 + cl) * 256 + ((kb ^ (cl & 7)) << 3)];
            acc[nt] = __builtin_amdgcn_mfma_f32_16x16x32_bf16(af, bf, acc[nt], 0, 0, 0);
        }
    }

    #pragma unroll
    for (int nt = 0; nt < 4; ++nt) {
        int j = jt * 64 + nt * 16 + cl;
        const float* bp = (j < 256) ? b0 : ((j < 512) ? b1 : b2);
        float bias = bp[j & 255];
        #pragma unroll
        for (int r = 0; r < 4; ++r) {
            float v = acc[nt][r] + bias;
            int m = mt * 64 + wv * 16 + qr * 4 + r;      // C/D: row=(lane>>4)*4+reg, col=lane&15
            if (o_mode == 0) {
                // scan-ordered XS: [t][wg][c:6][tid:256][8]
                int t = m >> 5, b = m & 31;
                int wgs = b >> 4, mm = b & 15, sqr = mm >> 2, sr = mm & 3;
                int gate = j >> 8, c = j & 255;
                int swv = c >> 6, snt = (c >> 4) & 3, scl = c & 15;
                int stid = swv * 64 + sqr * 16 + scl;
                int elem = gate * 16 + snt * 4 + sr;
                size_t off = (((size_t)((t * 2 + wgs) * 6 + (elem >> 3))) << 11)
                           + (size_t)stid * 8 + (elem & 7);
                ((unsigned short*)Optr)[off] = f2bf(v);
            } else {
                int tc = m >> 5, b = m & 31;
                ((float*)Optr)[(size_t)b * (SSZ * 256) + (size_t)(c0 + tc) * 256 + j] = v;
            }
        }
    }
}

// ---------------------------------------------------------------------------
// GRU scan, one time chunk. grid=2 WGs x 256 thr (4 waves), 16 samples each.
// Wave wv owns cols [wv*64, wv*64+64) as 4 n-tiles. All of Whz/Whr/Whg held as
// register B-fragments (3*4*8 short8 = 384 VGPR). LDS only for the h / h*r
// A-operand images (8 KB each, xor-swizzled). fp32 h master in registers.
// ---------------------------------------------------------------------------
__global__ __launch_bounds__(256, 1) void gru_scan(
    const unsigned short* __restrict__ XS,     // [TC][2][6][256][8] bf16
    unsigned short* __restrict__ Hout,         // [TC][32][256] bf16
    float* __restrict__ hstate,                // ws [2][32][256] fp32
    const float* __restrict__ hidden_in,       // d_in[1] [32][2][256] fp32
    const float* __restrict__ Whz, const float* __restrict__ Whr, const float* __restrict__ Whg,
    int layer, int first_chunk, int last_chunk,
    float* __restrict__ dout_tail)             // d_out + B*S*O, [32][2][256]
{
    __shared__ unsigned short hA[4096];        // h   [m:16][k:256] bf16, swizzled
    __shared__ unsigned short A2[4096];        // h*r [m:16][k:256]

    const int tid  = threadIdx.x;
    const int wg   = blockIdx.x;
    const int lane = tid & 63, wv = tid >> 6;  // 4 waves
    const int cl   = lane & 15, qr = lane >> 4;
    const int cb   = wv * 64;                  // wave's column base
    const int swl  = cl & 7;
    const int mrow = qr * 4;

    // all gate weights -> registers (B-frag: n = lane&15, k = (lane>>4)*8 + j)
    short8 wzf[4][8], wrf[4][8], wgf[4][8];
    #pragma unroll
    for (int nt = 0; nt < 4; ++nt) {
        int n = cb + nt * 16 + cl;
        #pragma unroll
        for (int kt = 0; kt < 8; ++kt) {
            int k0 = kt * 32 + qr * 8;
            wzf[nt][kt] = cvt8(Whz + (size_t)n * 256 + k0);
            wrf[nt][kt] = cvt8(Whr + (size_t)n * 256 + k0);
            wgf[nt][kt] = cvt8(Whg + (size_t)n * 256 + k0);
        }
    }

    // init h master (D-layout: m=qr*4+r, col=cb+nt*16+cl) + hA image
    float hreg[4][4];
    #pragma unroll
    for (int nt = 0; nt < 4; ++nt)
        #pragma unroll
        for (int r = 0; r < 4; ++r) {
            int m = mrow + r, b = wg * 16 + m, col = cb + nt * 16 + cl;
            float h = first_chunk ? hidden_in[(size_t)b * 512 + layer * 256 + col]
                                  : hstate[layer * 8192 + b * 256 + col];
            hreg[nt][r] = h;
            hA[m * 256 + ((((col >> 3) ^ (m & 7)) << 3) | (col & 7))] = f2bf(h);
        }
    __syncthreads();

    const unsigned short* xsb = XS + (size_t)wg * 6 * 2048 + (size_t)tid * 8;

    #pragma unroll 1
    for (int t = 0; t < TC; ++t) {
        // coalesced per-thread XS: 6 x 16B (elems: [gate:3][nt:4][r:4])
        const unsigned short* xp = xsb + (size_t)t * 24576;
        short8 xsv[6];
        #pragma unroll
        for (int c = 0; c < 6; ++c) xsv[c] = *(const short8*)(xp + c * 2048);

        // pass 1: z, r
        f32x4 az[4], ar[4];
        #pragma unroll
        for (int nt = 0; nt < 4; ++nt) { az[nt] = (f32x4){0.f,0.f,0.f,0.f}; ar[nt] = az[nt]; }
        #pragma unroll
        for (int kt = 0; kt < 8; ++kt) {
            int kb = kt * 4 + qr;
            short8 af = *(const short8*)&hA[cl * 256 + ((kb ^ swl) << 3)];
            #pragma unroll
            for (int nt = 0; nt < 4; ++nt) {
                az[nt] = __builtin_amdgcn_mfma_f32_16x16x32_bf16(af, wzf[nt][kt], az[nt], 0, 0, 0);
                ar[nt] = __builtin_amdgcn_mfma_f32_16x16x32_bf16(af, wrf[nt][kt], ar[nt], 0, 0, 0);
            }
        }
        float zs[4][4];
        #pragma unroll
        for (int nt = 0; nt < 4; ++nt)
            #pragma unroll
            for (int r = 0; r < 4; ++r) {
                int e = nt * 4 + r;
                float z = az[nt][r] + bf2f((unsigned short)xsv[e >> 3][e & 7]);
                zs[nt][r] = fsig(z);
                int e2 = 16 + e;
                float rr = ar[nt][r] + bf2f((unsigned short)xsv[e2 >> 3][e2 & 7]);
                rr = fsig(rr);
                int m = mrow + r, col = cb + nt * 16 + cl;
                A2[m * 256 + ((((col >> 3) ^ (m & 7)) << 3) | (col & 7))] = f2bf_ru(rr * hreg[nt][r]);
            }
        __syncthreads();

        // pass 2: g = (h*r) @ Whg^T
        f32x4 ag[4];
        #pragma unroll
        for (int nt = 0; nt < 4; ++nt) ag[nt] = (f32x4){0.f,0.f,0.f,0.f};
        #pragma unroll
        for (int kt = 0; kt < 8; ++kt) {
            int kb = kt * 4 + qr;
            short8 af = *(const short8*)&A2[cl * 256 + ((kb ^ swl) << 3)];
            #pragma unroll
            for (int nt = 0; nt < 4; ++nt)
                ag[nt] = __builtin_amdgcn_mfma_f32_16x16x32_bf16(af, wgf[nt][kt], ag[nt], 0, 0, 0);
        }
        #pragma unroll
        for (int nt = 0; nt < 4; ++nt)
            #pragma unroll
            for (int r = 0; r < 4; ++r) {
                int e = 32 + nt * 4 + r;
                float g = ag[nt][r] + bf2f((unsigned short)xsv[e >> 3][e & 7]);
                g = ftanh(g);
                float hn = zs[nt][r] * hreg[nt][r] + (1.0f - zs[nt][r]) * g;
                hreg[nt][r] = hn;
                int m = mrow + r, col = cb + nt * 16 + cl;
                hA[m * 256 + ((((col >> 3) ^ (m & 7)) << 3) | (col & 7))] = f2bf_ru(hn);
            }
        __syncthreads();

        // coalesced Hout[t] = h(t+1), staged via hA image (one 16-row slab/WG)
        {
            int m = tid >> 4, kb2 = (tid & 15) << 1;
            int x = m & 7;
            short8 r0 = *(const short8*)&hA[m * 256 + (((kb2)     ^ x) << 3)];
            short8 r1 = *(const short8*)&hA[m * 256 + (((kb2 + 1) ^ x) << 3)];
            unsigned short* hp = Hout + (size_t)(t * 32 + wg * 16 + m) * 256 + kb2 * 8;
            *(short8*)hp       = r0;
            *(short8*)(hp + 8) = r1;
        }
    }

    // persist state; emit final hidden on last chunk (fp32 master)
    #pragma unroll
    for (int nt = 0; nt < 4; ++nt)
        #pragma unroll
        for (int r = 0; r < 4; ++r) {
            int m = mrow + r, b = wg * 16 + m, col = cb + nt * 16 + cl;
            hstate[layer * 8192 + b * 256 + col] = hreg[nt][r];
            if (last_chunk)
                dout_tail[(size_t)b * 512 + layer * 256 + col] = hreg[nt][r];
        }
}

extern "C" void kernel_launch(void* const* d_in, const int* in_sizes, int n_in,
                              void* d_out, int out_size, void* d_ws, size_t ws_size,
                              hipStream_t stream) {
    const float* x   = (const float*)d_in[0];
    const float* h0  = (const float*)d_in[1];
    const float* Wxz = (const float*)d_in[2];
    const float* Whz = (const float*)d_in[3];
    const float* bz  = (const float*)d_in[4];
    const float* Wxr = (const float*)d_in[5];
    const float* Whr = (const float*)d_in[6];
    const float* br  = (const float*)d_in[7];
    const float* Wxg = (const float*)d_in[8];
    const float* Whg = (const float*)d_in[9];
    const float* bg  = (const float*)d_in[10];
    const float* Why = (const float*)d_in[11];
    const float* by  = (const float*)d_in[12];
    float* out = (float*)d_out;

    char* ws = (char*)d_ws;
    unsigned short* bufA = (unsigned short*)(ws);                    // 12,582,912 B
    unsigned short* bufB = (unsigned short*)(ws + 12582912);         // 12,582,912 B
    unsigned short* Hc0  = (unsigned short*)(ws + 25165824);         //  4,194,304 B
    unsigned short* Hc1  = (unsigned short*)(ws + 29360128);         //  4,194,304 B
    float*          hst  = (float*)(ws + 33554432);                  //     65,536 B
    float* dout_tail = out + (size_t)32 * 4096 * 256;

    const int LW = 256 * 256;   // per-layer weight stride
    for (int c = 0; c < NCHUNK; ++c) {
        int c0 = c * TC;
        int first = (c == 0), last = (c == NCHUNK - 1);
        xgemm<<<dim3(128, 12), 256, 0, stream>>>(x, 0, c0, Wxz, Wxr, Wxg, bz, br, bg,
                                                 768, bufA, 0);
        gru_scan<<<2, 256, 0, stream>>>(bufA, Hc0, hst, h0, Whz, Whr, Whg,
                                        0, first, last, dout_tail);
        xgemm<<<dim3(128, 12), 256, 0, stream>>>(Hc0, 1, c0, Wxz + LW, Wxr + LW, Wxg + LW,
                                                 bz + 256, br + 256, bg + 256, 768, bufB, 0);
        gru_scan<<<2, 256, 0, stream>>>(bufB, Hc1, hst, h0, Whz + LW, Whr + LW, Whg + LW,
                                        1, first, last, dout_tail);
        xgemm<<<dim3(128, 4), 256, 0, stream>>>(Hc1, 1, c0, Why, Why, Why, by, by, by,
                                                256, out, 1);
    }
}

// Round 3
// 29439.224 us; speedup vs baseline: 1.1384x; 1.0979x over previous
//
#include <hip/hip_runtime.h>

// ---------------------------------------------------------------------------
// MultilayerGRU: B=32, S=4096, H=256, O=256, L=2
// Round 3: TRANSPOSED scan matmuls (weights = A operand, h-image = B operand).
// D-frag gives each lane 4 consecutive n-columns of ONE sample -> packed bf16
// (v_perm) + ds_write_b64 for the h / h*r images. Sigmoid/tanh input scales
// folded into weights + xgemm epilogue (saves 1 mul/value).
// ---------------------------------------------------------------------------

typedef __attribute__((ext_vector_type(8))) short short8;
typedef __attribute__((ext_vector_type(4))) float f32x4;

#define TC      256
#define NCHUNK  16
#define SSZ     4096

#define SIGSC  (-1.44269504089f)   // -log2(e): sigmoid(x) = rcp(1+exp2(-log2e*x))
#define TANHSC ( 2.88539008178f)   // 2*log2(e): tanh(x) = 1 - 2*rcp(exp2(2log2e*x)+1)

__device__ __forceinline__ float bf2f(unsigned short u) {
    union { unsigned int i; float f; } v; v.i = ((unsigned int)u) << 16; return v.f;
}
__device__ __forceinline__ unsigned short f2bf(float f) {        // RNE (setup/xgemm)
    union { float f; unsigned int i; } v; v.f = f;
    v.i += 0x7fff + ((v.i >> 16) & 1);
    return (unsigned short)(v.i >> 16);
}
// pack two floats -> two bf16 (round-half-up) in one u32 via v_perm
__device__ __forceinline__ unsigned int pkbf(float lo, float hi) {
    union { float f; unsigned int i; } a, b; a.f = lo; b.f = hi;
    return __builtin_amdgcn_perm(b.i + 0x8000u, a.i + 0x8000u, 0x07060302);
}
__device__ __forceinline__ short8 cvt8s(const float* p, float s) {
    float4 a = *(const float4*)p;
    float4 b = *(const float4*)(p + 4);
    short8 r;
    r[0] = (short)f2bf(a.x * s); r[1] = (short)f2bf(a.y * s);
    r[2] = (short)f2bf(a.z * s); r[3] = (short)f2bf(a.w * s);
    r[4] = (short)f2bf(b.x * s); r[5] = (short)f2bf(b.y * s);
    r[6] = (short)f2bf(b.z * s); r[7] = (short)f2bf(b.w * s);
    return r;
}

// ---------------------------------------------------------------------------
// K=256 GEMM: out[i][j] = (sum_k A[i][k] * W[j][k] + bias[j]) * gate_scale
// a_mode 0: A = fp32 x ; a_mode 1: A = bf16 rows at i*256
// o_mode 0: bf16 store into scan-ordered XS [t][wg][c:6][tid:256][8], gate-scaled
// o_mode 1: fp32 store at b*(S*256) + (c0+tc)*256 + j (final y, unscaled)
// ---------------------------------------------------------------------------
__global__ __launch_bounds__(256, 2) void xgemm(
    const void* __restrict__ Aptr, int a_mode, int c0,
    const float* __restrict__ w0, const float* __restrict__ w1, const float* __restrict__ w2,
    const float* __restrict__ b0, const float* __restrict__ b1, const float* __restrict__ b2,
    int Ncols, void* __restrict__ Optr, int o_mode)
{
    __shared__ unsigned short Alds[64 * 256];
    __shared__ unsigned short Wlds[64 * 256];
    const int tid = threadIdx.x;
    const int mt = blockIdx.x, jt = blockIdx.y;

    for (int idx = tid; idx < 4096; idx += 256) {
        int row = idx >> 6;
        int kq  = (idx & 63) << 2;
        int sw  = row * 256 + (((((kq >> 3) ^ (row & 7)) << 3)) | (kq & 7));
        if (a_mode == 0) {
            int i = mt * 64 + row; int tc = i >> 5, b = i & 31;
            const float* p = (const float*)Aptr + ((size_t)b * SSZ + (size_t)(c0 + tc)) * 256 + kq;
            float4 v = *(const float4*)p;
            ushort4 u; u.x = f2bf(v.x); u.y = f2bf(v.y); u.z = f2bf(v.z); u.w = f2bf(v.w);
            *(ushort4*)&Alds[sw] = u;
        } else {
            const unsigned short* p = (const unsigned short*)Aptr + (size_t)(mt * 64 + row) * 256 + kq;
            *(ushort4*)&Alds[sw] = *(const ushort4*)p;
        }
    }
    for (int idx = tid; idx < 4096; idx += 256) {
        int row = idx >> 6;
        int kq  = (idx & 63) << 2;
        int j   = jt * 64 + row;
        const float* wp = (j < 256) ? w0 : ((j < 512) ? w1 : w2);
        const float* p  = wp + (size_t)(j & 255) * 256 + kq;
        float4 v = *(const float4*)p;
        ushort4 u; u.x = f2bf(v.x); u.y = f2bf(v.y); u.z = f2bf(v.z); u.w = f2bf(v.w);
        int sw = row * 256 + (((((kq >> 3) ^ (row & 7)) << 3)) | (kq & 7));
        *(ushort4*)&Wlds[sw] = u;
    }
    __syncthreads();

    const int lane = tid & 63, wv = tid >> 6;
    const int cl = lane & 15, qr = lane >> 4;
    f32x4 acc[4];
    #pragma unroll
    for (int nt = 0; nt < 4; ++nt) acc[nt] = (f32x4){0.f, 0.f, 0.f, 0.f};

    #pragma unroll
    for (int kt = 0; kt < 8; ++kt) {
        int kb = kt * 4 + qr;
        short8 af = *(const short8*)&Alds[(wv * 16 + cl) * 256 + ((kb ^ (cl & 7)) << 3)];
        #pragma unroll
        for (int nt = 0; nt < 4; ++nt) {
            short8 bf = *(const short8*)&Wlds[(nt * 16 + cl) * 256 + ((kb ^ (cl & 7)) << 3)];
            acc[nt] = __builtin_amdgcn_mfma_f32_16x16x32_bf16(af, bf, acc[nt], 0, 0, 0);
        }
    }

    #pragma unroll
    for (int nt = 0; nt < 4; ++nt) {
        int j = jt * 64 + nt * 16 + cl;
        const float* bp = (j < 256) ? b0 : ((j < 512) ? b1 : b2);
        float bias = bp[j & 255];
        #pragma unroll
        for (int r = 0; r < 4; ++r) {
            float v = acc[nt][r] + bias;
            int m = mt * 64 + wv * 16 + qr * 4 + r;      // C/D: row=(lane>>4)*4+reg, col=lane&15
            if (o_mode == 0) {
                int t = m >> 5, b = m & 31;
                int wgs = b >> 4, scl = b & 15;          // scan: sample -> lane cl
                int gate = j >> 8, c = j & 255;
                int swv = c >> 6, snt = (c >> 4) & 3, sqr = (c >> 2) & 3, sr = c & 3;
                int stid = swv * 64 + sqr * 16 + scl;
                int e = gate * 16 + snt * 4 + sr;
                size_t off = (((size_t)((t * 2 + wgs) * 6 + (e >> 3))) << 11)
                           + (size_t)stid * 8 + (e & 7);
                float gs = (gate < 2) ? SIGSC : TANHSC;
                ((unsigned short*)Optr)[off] = f2bf(v * gs);
            } else {
                int tc = m >> 5, b = m & 31;
                ((float*)Optr)[(size_t)b * (SSZ * 256) + (size_t)(c0 + tc) * 256 + j] = v;
            }
        }
    }
}

// ---------------------------------------------------------------------------
// GRU scan, transposed form. grid=2 WGs x 256 thr (4 waves), 16 samples each.
// P[n][b] = W[n,:]·h[b,:]: A-frag = weights (regs, pre-scaled), B-frag = h image
// in LDS [b:16][k:256] (xor-swizzled, b128 reads). D-frag: lane -> sample b=cl,
// 4 consecutive n per tile -> packed bf16 ds_write_b64 write-back.
// ---------------------------------------------------------------------------
__global__ __launch_bounds__(256, 1) void gru_scan(
    const unsigned short* __restrict__ XS,     // [TC][2][6][256][8] bf16, gate-scaled
    unsigned short* __restrict__ Hout,         // [TC][32][256] bf16
    float* __restrict__ hstate,                // ws [2][32][256] fp32
    const float* __restrict__ hidden_in,       // d_in[1] [32][2][256] fp32
    const float* __restrict__ Whz, const float* __restrict__ Whr, const float* __restrict__ Whg,
    int layer, int first_chunk, int last_chunk,
    float* __restrict__ dout_tail)             // d_out + B*S*O, [32][2][256]
{
    __shared__ unsigned short hA[4096];        // h   [b:16][n:256] bf16, swizzled
    __shared__ unsigned short A2[4096];        // h*r [b:16][n:256]

    const int tid  = threadIdx.x;
    const int wg   = blockIdx.x;
    const int lane = tid & 63, wv = tid >> 6;  // 4 waves
    const int cl   = lane & 15, qr = lane >> 4;
    const int swl  = cl & 7;
    const int b    = wg * 16 + cl;             // this lane's sample

    // weights as A-frags (pre-scaled): A[n][k], n = tile+cl, k = kt*32 + qr*8
    short8 wzf[4][8], wrf[4][8], wgf[4][8];
    #pragma unroll
    for (int nt = 0; nt < 4; ++nt) {
        int n = wv * 64 + nt * 16 + cl;
        #pragma unroll
        for (int kt = 0; kt < 8; ++kt) {
            int k0 = kt * 32 + qr * 8;
            wzf[nt][kt] = cvt8s(Whz + (size_t)n * 256 + k0, SIGSC);
            wrf[nt][kt] = cvt8s(Whr + (size_t)n * 256 + k0, SIGSC);
            wgf[nt][kt] = cvt8s(Whg + (size_t)n * 256 + k0, TANHSC);
        }
    }

    // per-nt invariant offsets (elements) for packed writes: 4 consecutive n
    int wro[4];
    #pragma unroll
    for (int nt = 0; nt < 4; ++nt) {
        int nb = wv * 64 + nt * 16 + qr * 4;
        wro[nt] = cl * 256 + ((((nb >> 3) ^ swl) << 3) | (nb & 4));
    }

    // h master: lane holds h[b][nb..nb+3] per tile (fp32), init hA image
    float hreg[4][4];
    #pragma unroll
    for (int nt = 0; nt < 4; ++nt) {
        int nb = wv * 64 + nt * 16 + qr * 4;
        float4 h4;
        if (first_chunk) h4 = *(const float4*)(hidden_in + (size_t)b * 512 + layer * 256 + nb);
        else             h4 = *(const float4*)(hstate + layer * 8192 + b * 256 + nb);
        hreg[nt][0] = h4.x; hreg[nt][1] = h4.y; hreg[nt][2] = h4.z; hreg[nt][3] = h4.w;
        uint2 p; p.x = pkbf(h4.x, h4.y); p.y = pkbf(h4.z, h4.w);
        *(uint2*)&hA[wro[nt]] = p;
    }
    __syncthreads();

    const unsigned short* xsb = XS + (size_t)wg * 6 * 2048 + (size_t)tid * 8;

    #pragma unroll 1
    for (int t = 0; t < TC; ++t) {
        const unsigned short* xp = xsb + (size_t)t * 24576;
        short8 xsv[6];
        #pragma unroll
        for (int c = 0; c < 6; ++c) xsv[c] = *(const short8*)(xp + c * 2048);

        // pass 1: z, r  (A = weights, B = h image)
        f32x4 az[4], ar[4];
        #pragma unroll
        for (int nt = 0; nt < 4; ++nt) { az[nt] = (f32x4){0.f,0.f,0.f,0.f}; ar[nt] = az[nt]; }
        #pragma unroll
        for (int kt = 0; kt < 8; ++kt) {
            int kb = kt * 4 + qr;
            short8 bf = *(const short8*)&hA[cl * 256 + ((kb ^ swl) << 3)];
            #pragma unroll
            for (int nt = 0; nt < 4; ++nt) {
                az[nt] = __builtin_amdgcn_mfma_f32_16x16x32_bf16(wzf[nt][kt], bf, az[nt], 0, 0, 0);
                ar[nt] = __builtin_amdgcn_mfma_f32_16x16x32_bf16(wrf[nt][kt], bf, ar[nt], 0, 0, 0);
            }
        }
        float zs[4][4];
        #pragma unroll
        for (int nt = 0; nt < 4; ++nt) {
            float a2v[4];
            #pragma unroll
            for (int r = 0; r < 4; ++r) {
                int e = nt * 4 + r;
                float sz = az[nt][r] + bf2f((unsigned short)xsv[e >> 3][e & 7]);
                zs[nt][r] = __builtin_amdgcn_rcpf(1.0f + __builtin_amdgcn_exp2f(sz));
                int e2 = 16 + e;
                float sr = ar[nt][r] + bf2f((unsigned short)xsv[e2 >> 3][e2 & 7]);
                float rr = __builtin_amdgcn_rcpf(1.0f + __builtin_amdgcn_exp2f(sr));
                a2v[r] = rr * hreg[nt][r];
            }
            uint2 p; p.x = pkbf(a2v[0], a2v[1]); p.y = pkbf(a2v[2], a2v[3]);
            *(uint2*)&A2[wro[nt]] = p;
        }
        __syncthreads();

        // pass 2: g = (h*r) @ Whg^T  (B = A2 image)
        f32x4 ag[4];
        #pragma unroll
        for (int nt = 0; nt < 4; ++nt) ag[nt] = (f32x4){0.f,0.f,0.f,0.f};
        #pragma unroll
        for (int kt = 0; kt < 8; ++kt) {
            int kb = kt * 4 + qr;
            short8 bf = *(const short8*)&A2[cl * 256 + ((kb ^ swl) << 3)];
            #pragma unroll
            for (int nt = 0; nt < 4; ++nt)
                ag[nt] = __builtin_amdgcn_mfma_f32_16x16x32_bf16(wgf[nt][kt], bf, ag[nt], 0, 0, 0);
        }
        #pragma unroll
        for (int nt = 0; nt < 4; ++nt) {
            float hn4[4];
            #pragma unroll
            for (int r = 0; r < 4; ++r) {
                int e = 32 + nt * 4 + r;
                float sg = ag[nt][r] + bf2f((unsigned short)xsv[e >> 3][e & 7]);
                float g = 1.0f - 2.0f * __builtin_amdgcn_rcpf(
                              1.0f + __builtin_amdgcn_exp2f(sg));
                float hn = g + zs[nt][r] * (hreg[nt][r] - g);
                hreg[nt][r] = hn;
                hn4[r] = hn;
            }
            uint2 p; p.x = pkbf(hn4[0], hn4[1]); p.y = pkbf(hn4[2], hn4[3]);
            *(uint2*)&hA[wro[nt]] = p;
        }
        __syncthreads();

        // coalesced Hout[t] from hA image (rows = samples)
        {
            int m = tid >> 4, kb2 = (tid & 15) << 1;
            int x = m & 7;
            short8 r0 = *(const short8*)&hA[m * 256 + (((kb2)     ^ x) << 3)];
            short8 r1 = *(const short8*)&hA[m * 256 + (((kb2 + 1) ^ x) << 3)];
            unsigned short* hp = Hout + (size_t)(t * 32 + wg * 16 + m) * 256 + kb2 * 8;
            *(short8*)hp       = r0;
            *(short8*)(hp + 8) = r1;
        }
    }

    // persist state; emit final hidden on last chunk (fp32 master, float4)
    #pragma unroll
    for (int nt = 0; nt < 4; ++nt) {
        int nb = wv * 64 + nt * 16 + qr * 4;
        float4 h4; h4.x = hreg[nt][0]; h4.y = hreg[nt][1]; h4.z = hreg[nt][2]; h4.w = hreg[nt][3];
        *(float4*)(hstate + layer * 8192 + b * 256 + nb) = h4;
        if (last_chunk)
            *(float4*)(dout_tail + (size_t)b * 512 + layer * 256 + nb) = h4;
    }
}

extern "C" void kernel_launch(void* const* d_in, const int* in_sizes, int n_in,
                              void* d_out, int out_size, void* d_ws, size_t ws_size,
                              hipStream_t stream) {
    const float* x   = (const float*)d_in[0];
    const float* h0  = (const float*)d_in[1];
    const float* Wxz = (const float*)d_in[2];
    const float* Whz = (const float*)d_in[3];
    const float* bz  = (const float*)d_in[4];
    const float* Wxr = (const float*)d_in[5];
    const float* Whr = (const float*)d_in[6];
    const float* br  = (const float*)d_in[7];
    const float* Wxg = (const float*)d_in[8];
    const float* Whg = (const float*)d_in[9];
    const float* bg  = (const float*)d_in[10];
    const float* Why = (const float*)d_in[11];
    const float* by  = (const float*)d_in[12];
    float* out = (float*)d_out;

    char* ws = (char*)d_ws;
    unsigned short* bufA = (unsigned short*)(ws);                    // 12,582,912 B
    unsigned short* bufB = (unsigned short*)(ws + 12582912);         // 12,582,912 B
    unsigned short* Hc0  = (unsigned short*)(ws + 25165824);         //  4,194,304 B
    unsigned short* Hc1  = (unsigned short*)(ws + 29360128);         //  4,194,304 B
    float*          hst  = (float*)(ws + 33554432);                  //     65,536 B
    float* dout_tail = out + (size_t)32 * 4096 * 256;

    const int LW = 256 * 256;   // per-layer weight stride
    for (int c = 0; c < NCHUNK; ++c) {
        int c0 = c * TC;
        int first = (c == 0), last = (c == NCHUNK - 1);
        xgemm<<<dim3(128, 12), 256, 0, stream>>>(x, 0, c0, Wxz, Wxr, Wxg, bz, br, bg,
                                                 768, bufA, 0);
        gru_scan<<<2, 256, 0, stream>>>(bufA, Hc0, hst, h0, Whz, Whr, Whg,
                                        0, first, last, dout_tail);
        xgemm<<<dim3(128, 12), 256, 0, stream>>>(Hc0, 1, c0, Wxz + LW, Wxr + LW, Wxg + LW,
                                                 bz + 256, br + 256, bg + 256, 768, bufB, 0);
        gru_scan<<<2, 256, 0, stream>>>(bufB, Hc1, hst, h0, Whz + LW, Whr + LW, Whg + LW,
                                        1, first, last, dout_tail);
        xgemm<<<dim3(128, 4), 256, 0, stream>>>(Hc1, 1, c0, Why, Why, Why, by, by, by,
                                                256, out, 1);
    }
}

// Round 4
// 25655.405 us; speedup vs baseline: 1.3064x; 1.1475x over previous
//
#include <hip/hip_runtime.h>

// ---------------------------------------------------------------------------
// MultilayerGRU: B=32, S=4096, H=256, O=256, L=2
// Round 4: raw s_barrier (lgkmcnt-only drain — scan needs NO vmem ordering
// across barriers) + one-step XS register prefetch. Scan structure otherwise
// identical to round 3 (transposed matmuls, packed bf16 LDS writes).
// ---------------------------------------------------------------------------

typedef __attribute__((ext_vector_type(8))) short short8;
typedef __attribute__((ext_vector_type(4))) float f32x4;

#define TC      256
#define NCHUNK  16
#define SSZ     4096

#define SIGSC  (-1.44269504089f)   // -log2(e): sigmoid(x) = rcp(1+exp2(-log2e*x))
#define TANHSC ( 2.88539008178f)   // 2*log2(e): tanh(x) = 1 - 2*rcp(exp2(2log2e*x)+1)

__device__ __forceinline__ float bf2f(unsigned short u) {
    union { unsigned int i; float f; } v; v.i = ((unsigned int)u) << 16; return v.f;
}
__device__ __forceinline__ unsigned short f2bf(float f) {        // RNE (setup/xgemm)
    union { float f; unsigned int i; } v; v.f = f;
    v.i += 0x7fff + ((v.i >> 16) & 1);
    return (unsigned short)(v.i >> 16);
}
// pack two floats -> two bf16 (round-half-up) in one u32 via v_perm
__device__ __forceinline__ unsigned int pkbf(float lo, float hi) {
    union { float f; unsigned int i; } a, b; a.f = lo; b.f = hi;
    return __builtin_amdgcn_perm(b.i + 0x8000u, a.i + 0x8000u, 0x07060302);
}
__device__ __forceinline__ short8 cvt8s(const float* p, float s) {
    float4 a = *(const float4*)p;
    float4 b = *(const float4*)(p + 4);
    short8 r;
    r[0] = (short)f2bf(a.x * s); r[1] = (short)f2bf(a.y * s);
    r[2] = (short)f2bf(a.z * s); r[3] = (short)f2bf(a.w * s);
    r[4] = (short)f2bf(b.x * s); r[5] = (short)f2bf(b.y * s);
    r[6] = (short)f2bf(b.z * s); r[7] = (short)f2bf(b.w * s);
    return r;
}
// LDS-only barrier: does NOT drain vmcnt (no cross-thread global ordering is
// needed inside gru_scan — XS written by an earlier kernel, Hout read by a
// later kernel, hstate thread-private).
__device__ __forceinline__ void wg_barrier() {
    asm volatile("s_waitcnt lgkmcnt(0)" ::: "memory");
    __builtin_amdgcn_s_barrier();
}

// ---------------------------------------------------------------------------
// K=256 GEMM: out[i][j] = (sum_k A[i][k] * W[j][k] + bias[j]) * gate_scale
// a_mode 0: A = fp32 x ; a_mode 1: A = bf16 rows at i*256
// o_mode 0: bf16 store into scan-ordered XS [t][wg][c:6][tid:256][8], gate-scaled
// o_mode 1: fp32 store at b*(S*256) + (c0+tc)*256 + j (final y, unscaled)
// ---------------------------------------------------------------------------
__global__ __launch_bounds__(256, 2) void xgemm(
    const void* __restrict__ Aptr, int a_mode, int c0,
    const float* __restrict__ w0, const float* __restrict__ w1, const float* __restrict__ w2,
    const float* __restrict__ b0, const float* __restrict__ b1, const float* __restrict__ b2,
    int Ncols, void* __restrict__ Optr, int o_mode)
{
    __shared__ unsigned short Alds[64 * 256];
    __shared__ unsigned short Wlds[64 * 256];
    const int tid = threadIdx.x;
    const int mt = blockIdx.x, jt = blockIdx.y;

    for (int idx = tid; idx < 4096; idx += 256) {
        int row = idx >> 6;
        int kq  = (idx & 63) << 2;
        int sw  = row * 256 + (((((kq >> 3) ^ (row & 7)) << 3)) | (kq & 7));
        if (a_mode == 0) {
            int i = mt * 64 + row; int tc = i >> 5, b = i & 31;
            const float* p = (const float*)Aptr + ((size_t)b * SSZ + (size_t)(c0 + tc)) * 256 + kq;
            float4 v = *(const float4*)p;
            ushort4 u; u.x = f2bf(v.x); u.y = f2bf(v.y); u.z = f2bf(v.z); u.w = f2bf(v.w);
            *(ushort4*)&Alds[sw] = u;
        } else {
            const unsigned short* p = (const unsigned short*)Aptr + (size_t)(mt * 64 + row) * 256 + kq;
            *(ushort4*)&Alds[sw] = *(const ushort4*)p;
        }
    }
    for (int idx = tid; idx < 4096; idx += 256) {
        int row = idx >> 6;
        int kq  = (idx & 63) << 2;
        int j   = jt * 64 + row;
        const float* wp = (j < 256) ? w0 : ((j < 512) ? w1 : w2);
        const float* p  = wp + (size_t)(j & 255) * 256 + kq;
        float4 v = *(const float4*)p;
        ushort4 u; u.x = f2bf(v.x); u.y = f2bf(v.y); u.z = f2bf(v.z); u.w = f2bf(v.w);
        int sw = row * 256 + (((((kq >> 3) ^ (row & 7)) << 3)) | (kq & 7));
        *(ushort4*)&Wlds[sw] = u;
    }
    __syncthreads();

    const int lane = tid & 63, wv = tid >> 6;
    const int cl = lane & 15, qr = lane >> 4;
    f32x4 acc[4];
    #pragma unroll
    for (int nt = 0; nt < 4; ++nt) acc[nt] = (f32x4){0.f, 0.f, 0.f, 0.f};

    #pragma unroll
    for (int kt = 0; kt < 8; ++kt) {
        int kb = kt * 4 + qr;
        short8 af = *(const short8*)&Alds[(wv * 16 + cl) * 256 + ((kb ^ (cl & 7)) << 3)];
        #pragma unroll
        for (int nt = 0; nt < 4; ++nt) {
            short8 bf = *(const short8*)&Wlds[(nt * 16 + cl) * 256 + ((kb ^ (cl & 7)) << 3)];
            acc[nt] = __builtin_amdgcn_mfma_f32_16x16x32_bf16(af, bf, acc[nt], 0, 0, 0);
        }
    }

    #pragma unroll
    for (int nt = 0; nt < 4; ++nt) {
        int j = jt * 64 + nt * 16 + cl;
        const float* bp = (j < 256) ? b0 : ((j < 512) ? b1 : b2);
        float bias = bp[j & 255];
        #pragma unroll
        for (int r = 0; r < 4; ++r) {
            float v = acc[nt][r] + bias;
            int m = mt * 64 + wv * 16 + qr * 4 + r;      // C/D: row=(lane>>4)*4+reg, col=lane&15
            if (o_mode == 0) {
                int t = m >> 5, b = m & 31;
                int wgs = b >> 4, scl = b & 15;          // scan: sample -> lane cl
                int gate = j >> 8, c = j & 255;
                int swv = c >> 6, snt = (c >> 4) & 3, sqr = (c >> 2) & 3, sr = c & 3;
                int stid = swv * 64 + sqr * 16 + scl;
                int e = gate * 16 + snt * 4 + sr;
                size_t off = (((size_t)((t * 2 + wgs) * 6 + (e >> 3))) << 11)
                           + (size_t)stid * 8 + (e & 7);
                float gs = (gate < 2) ? SIGSC : TANHSC;
                ((unsigned short*)Optr)[off] = f2bf(v * gs);
            } else {
                int tc = m >> 5, b = m & 31;
                ((float*)Optr)[(size_t)b * (SSZ * 256) + (size_t)(c0 + tc) * 256 + j] = v;
            }
        }
    }
}

// ---------------------------------------------------------------------------
// GRU scan, transposed form. grid=2 WGs x 256 thr (4 waves), 16 samples each.
// Raw lgkm-only barriers keep XS loads / Hout stores in flight across steps;
// XS[t+1] register-prefetched at iteration top.
// ---------------------------------------------------------------------------
__global__ __launch_bounds__(256, 1) void gru_scan(
    const unsigned short* __restrict__ XS,     // [TC][2][6][256][8] bf16, gate-scaled
    unsigned short* __restrict__ Hout,         // [TC][32][256] bf16
    float* __restrict__ hstate,                // ws [2][32][256] fp32
    const float* __restrict__ hidden_in,       // d_in[1] [32][2][256] fp32
    const float* __restrict__ Whz, const float* __restrict__ Whr, const float* __restrict__ Whg,
    int layer, int first_chunk, int last_chunk,
    float* __restrict__ dout_tail)             // d_out + B*S*O, [32][2][256]
{
    __shared__ unsigned short hA[4096];        // h   [b:16][n:256] bf16, swizzled
    __shared__ unsigned short A2[4096];        // h*r [b:16][n:256]

    const int tid  = threadIdx.x;
    const int wg   = blockIdx.x;
    const int lane = tid & 63, wv = tid >> 6;  // 4 waves
    const int cl   = lane & 15, qr = lane >> 4;
    const int swl  = cl & 7;
    const int b    = wg * 16 + cl;             // this lane's sample

    // weights as A-frags (pre-scaled): A[n][k], n = tile+cl, k = kt*32 + qr*8
    short8 wzf[4][8], wrf[4][8], wgf[4][8];
    #pragma unroll
    for (int nt = 0; nt < 4; ++nt) {
        int n = wv * 64 + nt * 16 + cl;
        #pragma unroll
        for (int kt = 0; kt < 8; ++kt) {
            int k0 = kt * 32 + qr * 8;
            wzf[nt][kt] = cvt8s(Whz + (size_t)n * 256 + k0, SIGSC);
            wrf[nt][kt] = cvt8s(Whr + (size_t)n * 256 + k0, SIGSC);
            wgf[nt][kt] = cvt8s(Whg + (size_t)n * 256 + k0, TANHSC);
        }
    }

    // per-nt invariant offsets (elements) for packed writes: 4 consecutive n
    int wro[4];
    #pragma unroll
    for (int nt = 0; nt < 4; ++nt) {
        int nb = wv * 64 + nt * 16 + qr * 4;
        wro[nt] = cl * 256 + ((((nb >> 3) ^ swl) << 3) | (nb & 4));
    }

    // h master: lane holds h[b][nb..nb+3] per tile (fp32), init hA image
    float hreg[4][4];
    #pragma unroll
    for (int nt = 0; nt < 4; ++nt) {
        int nb = wv * 64 + nt * 16 + qr * 4;
        float4 h4;
        if (first_chunk) h4 = *(const float4*)(hidden_in + (size_t)b * 512 + layer * 256 + nb);
        else             h4 = *(const float4*)(hstate + layer * 8192 + b * 256 + nb);
        hreg[nt][0] = h4.x; hreg[nt][1] = h4.y; hreg[nt][2] = h4.z; hreg[nt][3] = h4.w;
        uint2 p; p.x = pkbf(h4.x, h4.y); p.y = pkbf(h4.z, h4.w);
        *(uint2*)&hA[wro[nt]] = p;
    }
    wg_barrier();

    const unsigned short* xsb = XS + (size_t)wg * 6 * 2048 + (size_t)tid * 8;

    // preload step 0's XS
    short8 xcur[6];
    #pragma unroll
    for (int c = 0; c < 6; ++c) xcur[c] = *(const short8*)(xsb + c * 2048);

    #pragma unroll 1
    for (int t = 0; t < TC; ++t) {
        // prefetch step t+1 (last iteration reloads t — harmless, stays in bounds)
        const unsigned short* xpn = xsb + (size_t)((t + 1 < TC) ? t + 1 : t) * 24576;
        short8 xnxt[6];
        #pragma unroll
        for (int c = 0; c < 6; ++c) xnxt[c] = *(const short8*)(xpn + c * 2048);

        // pass 1: z, r  (A = weights, B = h image)
        f32x4 az[4], ar[4];
        #pragma unroll
        for (int nt = 0; nt < 4; ++nt) { az[nt] = (f32x4){0.f,0.f,0.f,0.f}; ar[nt] = az[nt]; }
        #pragma unroll
        for (int kt = 0; kt < 8; ++kt) {
            int kb = kt * 4 + qr;
            short8 bf = *(const short8*)&hA[cl * 256 + ((kb ^ swl) << 3)];
            #pragma unroll
            for (int nt = 0; nt < 4; ++nt) {
                az[nt] = __builtin_amdgcn_mfma_f32_16x16x32_bf16(wzf[nt][kt], bf, az[nt], 0, 0, 0);
                ar[nt] = __builtin_amdgcn_mfma_f32_16x16x32_bf16(wrf[nt][kt], bf, ar[nt], 0, 0, 0);
            }
        }
        float zs[4][4];
        #pragma unroll
        for (int nt = 0; nt < 4; ++nt) {
            float a2v[4];
            #pragma unroll
            for (int r = 0; r < 4; ++r) {
                int e = nt * 4 + r;
                float sz = az[nt][r] + bf2f((unsigned short)xcur[e >> 3][e & 7]);
                zs[nt][r] = __builtin_amdgcn_rcpf(1.0f + __builtin_amdgcn_exp2f(sz));
                int e2 = 16 + e;
                float sr = ar[nt][r] + bf2f((unsigned short)xcur[e2 >> 3][e2 & 7]);
                float rr = __builtin_amdgcn_rcpf(1.0f + __builtin_amdgcn_exp2f(sr));
                a2v[r] = rr * hreg[nt][r];
            }
            uint2 p; p.x = pkbf(a2v[0], a2v[1]); p.y = pkbf(a2v[2], a2v[3]);
            *(uint2*)&A2[wro[nt]] = p;
        }
        wg_barrier();

        // pass 2: g = (h*r) @ Whg^T  (B = A2 image)
        f32x4 ag[4];
        #pragma unroll
        for (int nt = 0; nt < 4; ++nt) ag[nt] = (f32x4){0.f,0.f,0.f,0.f};
        #pragma unroll
        for (int kt = 0; kt < 8; ++kt) {
            int kb = kt * 4 + qr;
            short8 bf = *(const short8*)&A2[cl * 256 + ((kb ^ swl) << 3)];
            #pragma unroll
            for (int nt = 0; nt < 4; ++nt)
                ag[nt] = __builtin_amdgcn_mfma_f32_16x16x32_bf16(wgf[nt][kt], bf, ag[nt], 0, 0, 0);
        }
        #pragma unroll
        for (int nt = 0; nt < 4; ++nt) {
            float hn4[4];
            #pragma unroll
            for (int r = 0; r < 4; ++r) {
                int e = 32 + nt * 4 + r;
                float sg = ag[nt][r] + bf2f((unsigned short)xcur[e >> 3][e & 7]);
                float g = 1.0f - 2.0f * __builtin_amdgcn_rcpf(
                              1.0f + __builtin_amdgcn_exp2f(sg));
                float hn = g + zs[nt][r] * (hreg[nt][r] - g);
                hreg[nt][r] = hn;
                hn4[r] = hn;
            }
            uint2 p; p.x = pkbf(hn4[0], hn4[1]); p.y = pkbf(hn4[2], hn4[3]);
            *(uint2*)&hA[wro[nt]] = p;
        }
        wg_barrier();

        // coalesced Hout[t] from hA image (rows = samples); store left in flight
        {
            int m = tid >> 4, kb2 = (tid & 15) << 1;
            int x = m & 7;
            short8 r0 = *(const short8*)&hA[m * 256 + (((kb2)     ^ x) << 3)];
            short8 r1 = *(const short8*)&hA[m * 256 + (((kb2 + 1) ^ x) << 3)];
            unsigned short* hp = Hout + (size_t)(t * 32 + wg * 16 + m) * 256 + kb2 * 8;
            *(short8*)hp       = r0;
            *(short8*)(hp + 8) = r1;
        }

        // rotate prefetch
        #pragma unroll
        for (int c = 0; c < 6; ++c) xcur[c] = xnxt[c];
    }

    // persist state; emit final hidden on last chunk (fp32 master, float4)
    #pragma unroll
    for (int nt = 0; nt < 4; ++nt) {
        int nb = wv * 64 + nt * 16 + qr * 4;
        float4 h4; h4.x = hreg[nt][0]; h4.y = hreg[nt][1]; h4.z = hreg[nt][2]; h4.w = hreg[nt][3];
        *(float4*)(hstate + layer * 8192 + b * 256 + nb) = h4;
        if (last_chunk)
            *(float4*)(dout_tail + (size_t)b * 512 + layer * 256 + nb) = h4;
    }
}

extern "C" void kernel_launch(void* const* d_in, const int* in_sizes, int n_in,
                              void* d_out, int out_size, void* d_ws, size_t ws_size,
                              hipStream_t stream) {
    const float* x   = (const float*)d_in[0];
    const float* h0  = (const float*)d_in[1];
    const float* Wxz = (const float*)d_in[2];
    const float* Whz = (const float*)d_in[3];
    const float* bz  = (const float*)d_in[4];
    const float* Wxr = (const float*)d_in[5];
    const float* Whr = (const float*)d_in[6];
    const float* br  = (const float*)d_in[7];
    const float* Wxg = (const float*)d_in[8];
    const float* Whg = (const float*)d_in[9];
    const float* bg  = (const float*)d_in[10];
    const float* Why = (const float*)d_in[11];
    const float* by  = (const float*)d_in[12];
    float* out = (float*)d_out;

    char* ws = (char*)d_ws;
    unsigned short* bufA = (unsigned short*)(ws);                    // 12,582,912 B
    unsigned short* bufB = (unsigned short*)(ws + 12582912);         // 12,582,912 B
    unsigned short* Hc0  = (unsigned short*)(ws + 25165824);         //  4,194,304 B
    unsigned short* Hc1  = (unsigned short*)(ws + 29360128);         //  4,194,304 B
    float*          hst  = (float*)(ws + 33554432);                  //     65,536 B
    float* dout_tail = out + (size_t)32 * 4096 * 256;

    const int LW = 256 * 256;   // per-layer weight stride
    for (int c = 0; c < NCHUNK; ++c) {
        int c0 = c * TC;
        int first = (c == 0), last = (c == NCHUNK - 1);
        xgemm<<<dim3(128, 12), 256, 0, stream>>>(x, 0, c0, Wxz, Wxr, Wxg, bz, br, bg,
                                                 768, bufA, 0);
        gru_scan<<<2, 256, 0, stream>>>(bufA, Hc0, hst, h0, Whz, Whr, Whg,
                                        0, first, last, dout_tail);
        xgemm<<<dim3(128, 12), 256, 0, stream>>>(Hc0, 1, c0, Wxz + LW, Wxr + LW, Wxg + LW,
                                                 bz + 256, br + 256, bg + 256, 768, bufB, 0);
        gru_scan<<<2, 256, 0, stream>>>(bufB, Hc1, hst, h0, Whz + LW, Whr + LW, Whg + LW,
                                        1, first, last, dout_tail);
        xgemm<<<dim3(128, 4), 256, 0, stream>>>(Hc1, 1, c0, Why, Why, Why, by, by, by,
                                                256, out, 1);
    }
}

// Round 5
// 14817.409 us; speedup vs baseline: 2.2619x; 1.7314x over previous
//
#include <hip/hip_runtime.h>

// ---------------------------------------------------------------------------
// MultilayerGRU: B=32, S=4096, H=256, O=256, L=2
// Round 5: chunk-pipelined LAYER OVERLAP. Per iteration i:
//   gemm3     : one dispatch computing XS0(i) | XS1(i-1) | y(i-2)   (role by jt)
//   scan_dual : 4 WGs = layer-0 scan of chunk i (2 WGs) + layer-1 scan of
//               chunk i-1 (2 WGs) — independent, disjoint CUs, overlap fully.
// Scan body identical to round 4 (transposed MFMA, lgkm-only barriers,
// XS register prefetch). Stream order enforces all chunk dependencies.
// ---------------------------------------------------------------------------

typedef __attribute__((ext_vector_type(8))) short short8;
typedef __attribute__((ext_vector_type(4))) float f32x4;

#define TC      256
#define NCHUNK  16
#define SSZ     4096
#define LW      (256*256)

#define SIGSC  (-1.44269504089f)   // -log2(e): sigmoid(x) = rcp(1+exp2(-log2e*x))
#define TANHSC ( 2.88539008178f)   // 2*log2(e): tanh(x) = 1 - 2*rcp(exp2(2log2e*x)+1)

__device__ __forceinline__ float bf2f(unsigned short u) {
    union { unsigned int i; float f; } v; v.i = ((unsigned int)u) << 16; return v.f;
}
__device__ __forceinline__ unsigned short f2bf(float f) {        // RNE
    union { float f; unsigned int i; } v; v.f = f;
    v.i += 0x7fff + ((v.i >> 16) & 1);
    return (unsigned short)(v.i >> 16);
}
__device__ __forceinline__ unsigned int pkbf(float lo, float hi) {
    union { float f; unsigned int i; } a, b; a.f = lo; b.f = hi;
    return __builtin_amdgcn_perm(b.i + 0x8000u, a.i + 0x8000u, 0x07060302);
}
__device__ __forceinline__ short8 cvt8s(const float* p, float s) {
    float4 a = *(const float4*)p;
    float4 b = *(const float4*)(p + 4);
    short8 r;
    r[0] = (short)f2bf(a.x * s); r[1] = (short)f2bf(a.y * s);
    r[2] = (short)f2bf(a.z * s); r[3] = (short)f2bf(a.w * s);
    r[4] = (short)f2bf(b.x * s); r[5] = (short)f2bf(b.y * s);
    r[6] = (short)f2bf(b.z * s); r[7] = (short)f2bf(b.w * s);
    return r;
}
// LDS-only barrier: no vmcnt drain (no cross-thread global ordering needed
// inside the scan — XS from an earlier dispatch, Hout read by a later one).
__device__ __forceinline__ void wg_barrier() {
    asm volatile("s_waitcnt lgkmcnt(0)" ::: "memory");
    __builtin_amdgcn_s_barrier();
}

// ---------------------------------------------------------------------------
// Fused GEMM dispatch, role by blockIdx.y:
//   jt  0..11 : XS0(c)   = x-side layer 0, chunk c        (c <= 15)
//   jt 12..23 : XS1(c-1) = x-side layer 1 from Hc0        (1 <= c <= 16)
//   jt 24..27 : y(c-2)   = output projection from Hc1     (c >= 2)
// ---------------------------------------------------------------------------
__global__ __launch_bounds__(256, 2) void gemm3(
    const float* __restrict__ x,
    const unsigned short* __restrict__ Hc0, const unsigned short* __restrict__ Hc1,
    const float* __restrict__ Wxz, const float* __restrict__ Wxr, const float* __restrict__ Wxg,
    const float* __restrict__ bz,  const float* __restrict__ br,  const float* __restrict__ bg,
    const float* __restrict__ Why, const float* __restrict__ by,
    unsigned short* __restrict__ XS0, unsigned short* __restrict__ XS1,
    float* __restrict__ out, int c)
{
    __shared__ unsigned short Alds[64 * 256];
    __shared__ unsigned short Wlds[64 * 256];

    const int jt = blockIdx.y;
    const void* Aptr; int a_mode, c0abs = 0, o_mode, jtl;
    const float *w0, *w1, *w2, *b0, *b1, *b2; void* Optr;
    if (jt < 12) {
        if (c > 15) return;
        Aptr = x; a_mode = 0; c0abs = c * TC;
        w0 = Wxz; w1 = Wxr; w2 = Wxg; b0 = bz; b1 = br; b2 = bg;
        Optr = XS0; o_mode = 0; jtl = jt;
    } else if (jt < 24) {
        if (c < 1 || c > 16) return;
        Aptr = Hc0; a_mode = 1;
        w0 = Wxz + LW; w1 = Wxr + LW; w2 = Wxg + LW;
        b0 = bz + 256; b1 = br + 256; b2 = bg + 256;
        Optr = XS1; o_mode = 0; jtl = jt - 12;
    } else {
        if (c < 2) return;
        Aptr = Hc1; a_mode = 1; c0abs = (c - 2) * TC;
        w0 = Why; w1 = Why; w2 = Why; b0 = by; b1 = by; b2 = by;
        Optr = out; o_mode = 1; jtl = jt - 24;
    }

    const int tid = threadIdx.x;
    const int mt = blockIdx.x;

    for (int idx = tid; idx < 4096; idx += 256) {
        int row = idx >> 6;
        int kq  = (idx & 63) << 2;
        int sw  = row * 256 + (((((kq >> 3) ^ (row & 7)) << 3)) | (kq & 7));
        if (a_mode == 0) {
            int i = mt * 64 + row; int tc = i >> 5, b = i & 31;
            const float* p = (const float*)Aptr + ((size_t)b * SSZ + (size_t)(c0abs + tc)) * 256 + kq;
            float4 v = *(const float4*)p;
            ushort4 u; u.x = f2bf(v.x); u.y = f2bf(v.y); u.z = f2bf(v.z); u.w = f2bf(v.w);
            *(ushort4*)&Alds[sw] = u;
        } else {
            const unsigned short* p = (const unsigned short*)Aptr + (size_t)(mt * 64 + row) * 256 + kq;
            *(ushort4*)&Alds[sw] = *(const ushort4*)p;
        }
    }
    for (int idx = tid; idx < 4096; idx += 256) {
        int row = idx >> 6;
        int kq  = (idx & 63) << 2;
        int j   = jtl * 64 + row;
        const float* wp = (j < 256) ? w0 : ((j < 512) ? w1 : w2);
        const float* p  = wp + (size_t)(j & 255) * 256 + kq;
        float4 v = *(const float4*)p;
        ushort4 u; u.x = f2bf(v.x); u.y = f2bf(v.y); u.z = f2bf(v.z); u.w = f2bf(v.w);
        int sw = row * 256 + (((((kq >> 3) ^ (row & 7)) << 3)) | (kq & 7));
        *(ushort4*)&Wlds[sw] = u;
    }
    __syncthreads();

    const int lane = tid & 63, wv = tid >> 6;
    const int cl = lane & 15, qr = lane >> 4;
    f32x4 acc[4];
    #pragma unroll
    for (int nt = 0; nt < 4; ++nt) acc[nt] = (f32x4){0.f, 0.f, 0.f, 0.f};

    #pragma unroll
    for (int kt = 0; kt < 8; ++kt) {
        int kb = kt * 4 + qr;
        short8 af = *(const short8*)&Alds[(wv * 16 + cl) * 256 + ((kb ^ (cl & 7)) << 3)];
        #pragma unroll
        for (int nt = 0; nt < 4; ++nt) {
            short8 bf = *(const short8*)&Wlds[(nt * 16 + cl) * 256 + ((kb ^ (cl & 7)) << 3)];
            acc[nt] = __builtin_amdgcn_mfma_f32_16x16x32_bf16(af, bf, acc[nt], 0, 0, 0);
        }
    }

    #pragma unroll
    for (int nt = 0; nt < 4; ++nt) {
        int j = jtl * 64 + nt * 16 + cl;
        const float* bp = (j < 256) ? b0 : ((j < 512) ? b1 : b2);
        float bias = bp[j & 255];
        #pragma unroll
        for (int r = 0; r < 4; ++r) {
            float v = acc[nt][r] + bias;
            int m = mt * 64 + wv * 16 + qr * 4 + r;      // C/D: row=(lane>>4)*4+reg, col=lane&15
            if (o_mode == 0) {
                int t = m >> 5, b = m & 31;
                int wgs = b >> 4, scl = b & 15;          // scan: sample -> lane cl
                int gate = j >> 8, cc = j & 255;
                int swv = cc >> 6, snt = (cc >> 4) & 3, sqr = (cc >> 2) & 3, sr = cc & 3;
                int stid = swv * 64 + sqr * 16 + scl;
                int e = gate * 16 + snt * 4 + sr;
                size_t off = (((size_t)((t * 2 + wgs) * 6 + (e >> 3))) << 11)
                           + (size_t)stid * 8 + (e & 7);
                float gs = (gate < 2) ? SIGSC : TANHSC;
                ((unsigned short*)Optr)[off] = f2bf(v * gs);
            } else {
                int tc = m >> 5, b = m & 31;
                ((float*)Optr)[(size_t)b * (SSZ * 256) + (size_t)(c0abs + tc) * 256 + j] = v;
            }
        }
    }
}

// ---------------------------------------------------------------------------
// Dual-layer GRU scan: blockIdx 0,1 -> layer 0 chunk c; 2,3 -> layer 1 chunk
// c-1. The two layer-scans are fully independent (different XS/Hout/weights/
// state) and run on disjoint CUs. Body identical to round 4.
// ---------------------------------------------------------------------------
__global__ __launch_bounds__(256, 1) void scan_dual(
    const unsigned short* __restrict__ XS0, const unsigned short* __restrict__ XS1,
    unsigned short* __restrict__ Hc0, unsigned short* __restrict__ Hc1,
    float* __restrict__ hstate,                // ws [2][32][256] fp32
    const float* __restrict__ hidden_in,       // d_in[1] [32][2][256] fp32
    const float* __restrict__ Whz0, const float* __restrict__ Whr0,
    const float* __restrict__ Whg0,
    int c, float* __restrict__ dout_tail)      // d_out + B*S*O, [32][2][256]
{
    __shared__ unsigned short hA[4096];        // h   [b:16][n:256] bf16, swizzled
    __shared__ unsigned short A2[4096];        // h*r [b:16][n:256]

    const int layer = blockIdx.x >> 1;
    const int wg    = blockIdx.x & 1;
    const int chunk = (layer == 0) ? c : c - 1;
    if (chunk < 0 || chunk > 15) return;

    const unsigned short* XS = (layer == 0) ? XS0 : XS1;
    unsigned short* Hout     = (layer == 0) ? Hc0 : Hc1;
    const float* Whz = Whz0 + (size_t)layer * LW;
    const float* Whr = Whr0 + (size_t)layer * LW;
    const float* Whg = Whg0 + (size_t)layer * LW;
    const int first_chunk = (chunk == 0), last_chunk = (chunk == NCHUNK - 1);

    const int tid  = threadIdx.x;
    const int lane = tid & 63, wv = tid >> 6;  // 4 waves
    const int cl   = lane & 15, qr = lane >> 4;
    const int swl  = cl & 7;
    const int b    = wg * 16 + cl;             // this lane's sample

    // weights as A-frags (pre-scaled): A[n][k], n = tile+cl, k = kt*32 + qr*8
    short8 wzf[4][8], wrf[4][8], wgf[4][8];
    #pragma unroll
    for (int nt = 0; nt < 4; ++nt) {
        int n = wv * 64 + nt * 16 + cl;
        #pragma unroll
        for (int kt = 0; kt < 8; ++kt) {
            int k0 = kt * 32 + qr * 8;
            wzf[nt][kt] = cvt8s(Whz + (size_t)n * 256 + k0, SIGSC);
            wrf[nt][kt] = cvt8s(Whr + (size_t)n * 256 + k0, SIGSC);
            wgf[nt][kt] = cvt8s(Whg + (size_t)n * 256 + k0, TANHSC);
        }
    }

    // per-nt invariant packed-write offsets: 4 consecutive n
    int wro[4];
    #pragma unroll
    for (int nt = 0; nt < 4; ++nt) {
        int nb = wv * 64 + nt * 16 + qr * 4;
        wro[nt] = cl * 256 + ((((nb >> 3) ^ swl) << 3) | (nb & 4));
    }

    // h master: lane holds h[b][nb..nb+3] per tile (fp32), init hA image
    float hreg[4][4];
    #pragma unroll
    for (int nt = 0; nt < 4; ++nt) {
        int nb = wv * 64 + nt * 16 + qr * 4;
        float4 h4;
        if (first_chunk) h4 = *(const float4*)(hidden_in + (size_t)b * 512 + layer * 256 + nb);
        else             h4 = *(const float4*)(hstate + layer * 8192 + b * 256 + nb);
        hreg[nt][0] = h4.x; hreg[nt][1] = h4.y; hreg[nt][2] = h4.z; hreg[nt][3] = h4.w;
        uint2 p; p.x = pkbf(h4.x, h4.y); p.y = pkbf(h4.z, h4.w);
        *(uint2*)&hA[wro[nt]] = p;
    }
    wg_barrier();

    const unsigned short* xsb = XS + (size_t)wg * 6 * 2048 + (size_t)tid * 8;

    // preload step 0's XS
    short8 xcur[6];
    #pragma unroll
    for (int cc = 0; cc < 6; ++cc) xcur[cc] = *(const short8*)(xsb + cc * 2048);

    #pragma unroll 1
    for (int t = 0; t < TC; ++t) {
        const unsigned short* xpn = xsb + (size_t)((t + 1 < TC) ? t + 1 : t) * 24576;
        short8 xnxt[6];
        #pragma unroll
        for (int cc = 0; cc < 6; ++cc) xnxt[cc] = *(const short8*)(xpn + cc * 2048);

        // pass 1: z, r  (A = weights, B = h image)
        f32x4 az[4], ar[4];
        #pragma unroll
        for (int nt = 0; nt < 4; ++nt) { az[nt] = (f32x4){0.f,0.f,0.f,0.f}; ar[nt] = az[nt]; }
        #pragma unroll
        for (int kt = 0; kt < 8; ++kt) {
            int kb = kt * 4 + qr;
            short8 bf = *(const short8*)&hA[cl * 256 + ((kb ^ swl) << 3)];
            #pragma unroll
            for (int nt = 0; nt < 4; ++nt) {
                az[nt] = __builtin_amdgcn_mfma_f32_16x16x32_bf16(wzf[nt][kt], bf, az[nt], 0, 0, 0);
                ar[nt] = __builtin_amdgcn_mfma_f32_16x16x32_bf16(wrf[nt][kt], bf, ar[nt], 0, 0, 0);
            }
        }
        float zs[4][4];
        #pragma unroll
        for (int nt = 0; nt < 4; ++nt) {
            float a2v[4];
            #pragma unroll
            for (int r = 0; r < 4; ++r) {
                int e = nt * 4 + r;
                float sz = az[nt][r] + bf2f((unsigned short)xcur[e >> 3][e & 7]);
                zs[nt][r] = __builtin_amdgcn_rcpf(1.0f + __builtin_amdgcn_exp2f(sz));
                int e2 = 16 + e;
                float sr = ar[nt][r] + bf2f((unsigned short)xcur[e2 >> 3][e2 & 7]);
                float rr = __builtin_amdgcn_rcpf(1.0f + __builtin_amdgcn_exp2f(sr));
                a2v[r] = rr * hreg[nt][r];
            }
            uint2 p; p.x = pkbf(a2v[0], a2v[1]); p.y = pkbf(a2v[2], a2v[3]);
            *(uint2*)&A2[wro[nt]] = p;
        }
        wg_barrier();

        // pass 2: g = (h*r) @ Whg^T  (B = A2 image)
        f32x4 ag[4];
        #pragma unroll
        for (int nt = 0; nt < 4; ++nt) ag[nt] = (f32x4){0.f,0.f,0.f,0.f};
        #pragma unroll
        for (int kt = 0; kt < 8; ++kt) {
            int kb = kt * 4 + qr;
            short8 bf = *(const short8*)&A2[cl * 256 + ((kb ^ swl) << 3)];
            #pragma unroll
            for (int nt = 0; nt < 4; ++nt)
                ag[nt] = __builtin_amdgcn_mfma_f32_16x16x32_bf16(wgf[nt][kt], bf, ag[nt], 0, 0, 0);
        }
        #pragma unroll
        for (int nt = 0; nt < 4; ++nt) {
            float hn4[4];
            #pragma unroll
            for (int r = 0; r < 4; ++r) {
                int e = 32 + nt * 4 + r;
                float sg = ag[nt][r] + bf2f((unsigned short)xcur[e >> 3][e & 7]);
                float g = 1.0f - 2.0f * __builtin_amdgcn_rcpf(
                              1.0f + __builtin_amdgcn_exp2f(sg));
                float hn = g + zs[nt][r] * (hreg[nt][r] - g);
                hreg[nt][r] = hn;
                hn4[r] = hn;
            }
            uint2 p; p.x = pkbf(hn4[0], hn4[1]); p.y = pkbf(hn4[2], hn4[3]);
            *(uint2*)&hA[wro[nt]] = p;
        }
        wg_barrier();

        // coalesced Hout[t] from hA image; store left in flight
        {
            int m = tid >> 4, kb2 = (tid & 15) << 1;
            int xx = m & 7;
            short8 r0 = *(const short8*)&hA[m * 256 + (((kb2)     ^ xx) << 3)];
            short8 r1 = *(const short8*)&hA[m * 256 + (((kb2 + 1) ^ xx) << 3)];
            unsigned short* hp = Hout + (size_t)(t * 32 + wg * 16 + m) * 256 + kb2 * 8;
            *(short8*)hp       = r0;
            *(short8*)(hp + 8) = r1;
        }

        #pragma unroll
        for (int cc = 0; cc < 6; ++cc) xcur[cc] = xnxt[cc];
    }

    // persist state; emit final hidden on last chunk
    #pragma unroll
    for (int nt = 0; nt < 4; ++nt) {
        int nb = wv * 64 + nt * 16 + qr * 4;
        float4 h4; h4.x = hreg[nt][0]; h4.y = hreg[nt][1]; h4.z = hreg[nt][2]; h4.w = hreg[nt][3];
        *(float4*)(hstate + layer * 8192 + b * 256 + nb) = h4;
        if (last_chunk)
            *(float4*)(dout_tail + (size_t)b * 512 + layer * 256 + nb) = h4;
    }
}

extern "C" void kernel_launch(void* const* d_in, const int* in_sizes, int n_in,
                              void* d_out, int out_size, void* d_ws, size_t ws_size,
                              hipStream_t stream) {
    const float* x   = (const float*)d_in[0];
    const float* h0  = (const float*)d_in[1];
    const float* Wxz = (const float*)d_in[2];
    const float* Whz = (const float*)d_in[3];
    const float* bz  = (const float*)d_in[4];
    const float* Wxr = (const float*)d_in[5];
    const float* Whr = (const float*)d_in[6];
    const float* br  = (const float*)d_in[7];
    const float* Wxg = (const float*)d_in[8];
    const float* Whg = (const float*)d_in[9];
    const float* bg  = (const float*)d_in[10];
    const float* Why = (const float*)d_in[11];
    const float* by  = (const float*)d_in[12];
    float* out = (float*)d_out;

    char* ws = (char*)d_ws;
    unsigned short* bufA = (unsigned short*)(ws);                    // XS0 12,582,912 B
    unsigned short* bufB = (unsigned short*)(ws + 12582912);         // XS1 12,582,912 B
    unsigned short* Hc0  = (unsigned short*)(ws + 25165824);         //  4,194,304 B
    unsigned short* Hc1  = (unsigned short*)(ws + 29360128);         //  4,194,304 B
    float*          hst  = (float*)(ws + 33554432);                  //     65,536 B
    float* dout_tail = out + (size_t)32 * 4096 * 256;

    // chunk-pipelined: iter i computes XS0(i), XS1(i-1), y(i-2) in one gemm
    // dispatch, then scans layer0(i) + layer1(i-1) concurrently.
    for (int i = 0; i <= 17; ++i) {
        gemm3<<<dim3(128, 28), 256, 0, stream>>>(x, Hc0, Hc1,
                                                 Wxz, Wxr, Wxg, bz, br, bg,
                                                 Why, by, bufA, bufB, out, i);
        if (i <= 16)
            scan_dual<<<4, 256, 0, stream>>>(bufA, bufB, Hc0, Hc1, hst, h0,
                                             Whz, Whr, Whg, i, dout_tail);
    }
}